// Round 1
// baseline (299.902 us; speedup 1.0000x reference)
//
#include <hip/hip_runtime.h>
#include <hip/hip_bf16.h>

// GraphSAGE 2-layer: gather+mean -> concat -> relu(X @ W^T), twice.
// Sizes: N_RAW=200000, N1=100000, N2=20000, K=10, D=256, OUT=256.

typedef __attribute__((ext_vector_type(8))) short bf16x8;
typedef __attribute__((ext_vector_type(4))) float f32x4;

__device__ __forceinline__ short f2bf(float f) {
  __hip_bfloat16 h = __float2bfloat16(f);
  return *reinterpret_cast<short*>(&h);
}
__device__ __forceinline__ float bf2f(short s) {
  union { unsigned u; float f; } x;
  x.u = ((unsigned)(unsigned short)s) << 16;
  return x.f;
}

// ---------------- W f32 -> bf16 ----------------
__global__ __launch_bounds__(256) void convert_w(const float* __restrict__ w,
                                                 short* __restrict__ wb, int n) {
  int i = blockIdx.x * 256 + threadIdx.x;
  if (i < n) wb[i] = f2bf(w[i]);
}

// ---------------- layer-1 gather+mean -> combined1 bf16 [100032][512] ----------------
// 256 threads = 4 sub-waves of 64; each 64-lane group does one node.
// Thread t (0..63) owns float4 column chunk t (cols 4t..4t+3 of 256).
__global__ __launch_bounds__(256) void build_combined1(
    const float* __restrict__ raw, const int* __restrict__ nodes1,
    const int* __restrict__ neigh1, short* __restrict__ comb) {
  const int i = blockIdx.x * 4 + (threadIdx.x >> 6);
  const int t = threadIdx.x & 63;
  const float4* raw4 = reinterpret_cast<const float4*>(raw);

  const int self = nodes1[i];
  float4 s = raw4[(size_t)self * 64 + t];
  float ax = 0.f, ay = 0.f, az = 0.f, aw = 0.f;
#pragma unroll
  for (int k = 0; k < 10; ++k) {
    const int nb = neigh1[i * 10 + k];
    float4 v = raw4[(size_t)nb * 64 + t];
    ax += v.x; ay += v.y; az += v.z; aw += v.w;
  }
  short* row = comb + (size_t)i * 512;
  short4 so; so.x = f2bf(s.x); so.y = f2bf(s.y); so.z = f2bf(s.z); so.w = f2bf(s.w);
  *reinterpret_cast<short4*>(row + t * 4) = so;
  short4 ao; ao.x = f2bf(ax * 0.1f); ao.y = f2bf(ay * 0.1f);
  ao.z = f2bf(az * 0.1f); ao.w = f2bf(aw * 0.1f);
  *reinterpret_cast<short4*>(row + 256 + t * 4) = ao;
}

// ---------------- layer-2 gather+mean on h1 (bf16) -> combined2 bf16 [20032][512] ----------------
__global__ __launch_bounds__(256) void build_combined2(
    const short* __restrict__ h1, const int* __restrict__ self2,
    const int* __restrict__ neigh2, short* __restrict__ comb) {
  const int i = blockIdx.x * 4 + (threadIdx.x >> 6);
  const int t = threadIdx.x & 63;

  const int self = self2[i];
  short4 sv = *reinterpret_cast<const short4*>(h1 + (size_t)self * 256 + t * 4);
  float ax = 0.f, ay = 0.f, az = 0.f, aw = 0.f;
#pragma unroll
  for (int k = 0; k < 10; ++k) {
    const int nb = neigh2[i * 10 + k];
    short4 v = *reinterpret_cast<const short4*>(h1 + (size_t)nb * 256 + t * 4);
    ax += bf2f(v.x); ay += bf2f(v.y); az += bf2f(v.z); aw += bf2f(v.w);
  }
  short* row = comb + (size_t)i * 512;
  *reinterpret_cast<short4*>(row + t * 4) = sv;  // bf16->bf16 passthrough
  short4 ao; ao.x = f2bf(ax * 0.1f); ao.y = f2bf(ay * 0.1f);
  ao.z = f2bf(az * 0.1f); ao.w = f2bf(aw * 0.1f);
  *reinterpret_cast<short4*>(row + 256 + t * 4) = ao;
}

// ---------------- GEMM: C[M][256] = relu(A[Mpad][512] @ B^T), B = W [256][512] bf16 ----------------
// 64x64 tile, BK=32, 4 waves, each wave 2x2 frags of 16x16x32 MFMA.
template <bool OUT_BF16>
__global__ __launch_bounds__(256) void sage_gemm(const short* __restrict__ A,
                                                 const short* __restrict__ B,
                                                 void* __restrict__ Cout,
                                                 int Mstore) {
  __shared__ short As[64][40];  // +8 pad: stride 80B -> only free 2-way conflicts
  __shared__ short Bs[64][40];  // Bs[n][k]

  const int tid = threadIdx.x;
  const int m0 = blockIdx.x * 64;
  const int n0 = blockIdx.y * 64;
  const int wave = tid >> 6, lane = tid & 63;
  const int wm = (wave >> 1) * 32, wn = (wave & 1) * 32;
  const int lr = lane & 15;              // m (or n) within 16x16 frag
  const int lk = (lane >> 4) * 8;        // k base within 32
  const int srow = tid >> 2, sseg = (tid & 3) * 8;

  f32x4 acc[2][2] = {};

  for (int k0 = 0; k0 < 512; k0 += 32) {
    bf16x8 av = *reinterpret_cast<const bf16x8*>(A + (size_t)(m0 + srow) * 512 + k0 + sseg);
    bf16x8 bv = *reinterpret_cast<const bf16x8*>(B + (size_t)(n0 + srow) * 512 + k0 + sseg);
    *reinterpret_cast<bf16x8*>(&As[srow][sseg]) = av;
    *reinterpret_cast<bf16x8*>(&Bs[srow][sseg]) = bv;
    __syncthreads();

    bf16x8 a0 = *reinterpret_cast<const bf16x8*>(&As[wm + lr][lk]);
    bf16x8 a1 = *reinterpret_cast<const bf16x8*>(&As[wm + 16 + lr][lk]);
    bf16x8 b0 = *reinterpret_cast<const bf16x8*>(&Bs[wn + lr][lk]);
    bf16x8 b1 = *reinterpret_cast<const bf16x8*>(&Bs[wn + 16 + lr][lk]);

    acc[0][0] = __builtin_amdgcn_mfma_f32_16x16x32_bf16(a0, b0, acc[0][0], 0, 0, 0);
    acc[0][1] = __builtin_amdgcn_mfma_f32_16x16x32_bf16(a0, b1, acc[0][1], 0, 0, 0);
    acc[1][0] = __builtin_amdgcn_mfma_f32_16x16x32_bf16(a1, b0, acc[1][0], 0, 0, 0);
    acc[1][1] = __builtin_amdgcn_mfma_f32_16x16x32_bf16(a1, b1, acc[1][1], 0, 0, 0);
    __syncthreads();
  }

#pragma unroll
  for (int mi = 0; mi < 2; ++mi)
#pragma unroll
    for (int ni = 0; ni < 2; ++ni)
#pragma unroll
      for (int r = 0; r < 4; ++r) {
        const int gm = m0 + wm + mi * 16 + (lane >> 4) * 4 + r;
        const int gn = n0 + wn + ni * 16 + lr;
        float v = acc[mi][ni][r];
        v = v > 0.f ? v : 0.f;  // fused relu
        if (gm < Mstore) {
          if (OUT_BF16)
            reinterpret_cast<short*>(Cout)[(size_t)gm * 256 + gn] = f2bf(v);
          else
            reinterpret_cast<float*>(Cout)[(size_t)gm * 256 + gn] = v;
        }
      }
}

extern "C" void kernel_launch(void* const* d_in, const int* in_sizes, int n_in,
                              void* d_out, int out_size, void* d_ws, size_t ws_size,
                              hipStream_t stream) {
  const float* raw = (const float*)d_in[0];
  const float* W1 = (const float*)d_in[1];
  const float* W2 = (const float*)d_in[2];
  const int* nodes1 = (const int*)d_in[3];
  const int* neigh1 = (const int*)d_in[4];
  const int* self2 = (const int*)d_in[5];
  const int* neigh2 = (const int*)d_in[6];
  float* out = (float*)d_out;

  const int N1 = 100000, N2 = 20000;
  const int M1p = 100032, M2p = 20032;  // padded to multiples of 64

  short* comb1 = (short*)d_ws;                       // M1p*512 bf16
  short* h1 = comb1 + (size_t)M1p * 512;             // M1p*256 bf16
  short* comb2 = h1 + (size_t)M1p * 256;             // M2p*512 bf16
  short* W1b = comb2 + (size_t)M2p * 512;            // 131072 bf16
  short* W2b = W1b + 131072;                         // 131072 bf16

  convert_w<<<512, 256, 0, stream>>>(W1, W1b, 131072);
  convert_w<<<512, 256, 0, stream>>>(W2, W2b, 131072);

  build_combined1<<<N1 / 4, 256, 0, stream>>>(raw, nodes1, neigh1, comb1);
  sage_gemm<true><<<dim3(M1p / 64, 4), 256, 0, stream>>>(comb1, W1b, h1, M1p);
  build_combined2<<<N2 / 4, 256, 0, stream>>>(h1, self2, neigh2, comb2);
  sage_gemm<false><<<dim3(M2p / 64, 4), 256, 0, stream>>>(comb2, W2b, out, N2);
}

// Round 2
// 244.414 us; speedup vs baseline: 1.2270x; 1.2270x over previous
//
#include <hip/hip_runtime.h>
#include <hip/hip_bf16.h>

// GraphSAGE 2-layer, fused: per-block {gather+mean -> LDS} then {MFMA GEMM}.
// Sizes: N_RAW=200000, N1=100000, N2=20000, K=10, D=256, OUT=256.
// 100000 = 3125*32, 20000 = 625*32 -> exact 32-row blocks.

typedef __attribute__((ext_vector_type(8))) short bf16x8;
typedef __attribute__((ext_vector_type(4))) float f32x4;

__device__ __forceinline__ short f2bf(float f) {
  __hip_bfloat16 h = __float2bfloat16(f);
  return *reinterpret_cast<short*>(&h);
}
__device__ __forceinline__ float bf2f(short s) {
  union { unsigned u; float f; } x;
  x.u = ((unsigned)(unsigned short)s) << 16;
  return x.f;
}

// ---------------- W f32 -> bf16 (tiny) ----------------
__global__ __launch_bounds__(256) void convert_w(const float* __restrict__ w,
                                                 short* __restrict__ wb, int n) {
  int i = blockIdx.x * 256 + threadIdx.x;
  if (i < n) wb[i] = f2bf(w[i]);
}

// ---------------- raw f32 [200000][256] -> bf16 ----------------
// one 8-elem chunk per thread; 25000 blocks.
__global__ __launch_bounds__(256) void convert_raw(const float* __restrict__ in,
                                                   short* __restrict__ out) {
  const size_t i = (size_t)blockIdx.x * 256 + threadIdx.x;  // chunk index
  const float4* in4 = reinterpret_cast<const float4*>(in);
  float4 u = in4[i * 2], v = in4[i * 2 + 1];
  bf16x8 o;
  o[0] = f2bf(u.x); o[1] = f2bf(u.y); o[2] = f2bf(u.z); o[3] = f2bf(u.w);
  o[4] = f2bf(v.x); o[5] = f2bf(v.y); o[6] = f2bf(v.z); o[7] = f2bf(v.w);
  reinterpret_cast<bf16x8*>(out)[i] = o;
}

// ---------------- fused layer: gather+mean -> LDS -> relu(comb @ W^T) ----------------
// Block: 32 rows x 256 cols, 256 threads (4 waves, each wave 32x64).
// LDS: As[32][520] bf16 (pad 8 -> row stride 1040 B, bank +4/row: conflict-free-ish).
// B-frags read straight from global W (256 KB, L2-resident). No K-loop barriers.
template <bool OUT_BF16>
__global__ __launch_bounds__(256) void sage_fused(
    const short* __restrict__ E,        // [Ne][256] bf16 embeddings
    const int* __restrict__ self_idx,   // [Nv]
    const int* __restrict__ neigh,      // [Nv][10]
    const short* __restrict__ Wb,       // [256][512] bf16
    void* __restrict__ out,             // [Nv][256] (bf16 or f32)
    int Nvalid) {
  __shared__ short As[32][520];

  const int tid = threadIdx.x;
  const int m0 = blockIdx.x * 32;

  // ---- gather + mean phase ----
  {
    const int c = tid & 31;    // 16-B chunk (8 bf16) within 256-col row
    const int rs = tid >> 5;   // row slot 0..7, handles rows rs*4..rs*4+3
#pragma unroll
    for (int rr = 0; rr < 4; ++rr) {
      const int r = rs * 4 + rr;
      const int gr = m0 + r;
      if (gr < Nvalid) {
        const int si = self_idx[gr];
        bf16x8 sv = *reinterpret_cast<const bf16x8*>(E + (size_t)si * 256 + c * 8);
        float a0 = 0.f, a1 = 0.f, a2 = 0.f, a3 = 0.f,
              a4 = 0.f, a5 = 0.f, a6 = 0.f, a7 = 0.f;
#pragma unroll
        for (int k = 0; k < 10; ++k) {
          const int nb = neigh[(size_t)gr * 10 + k];
          bf16x8 v = *reinterpret_cast<const bf16x8*>(E + (size_t)nb * 256 + c * 8);
          a0 += bf2f(v[0]); a1 += bf2f(v[1]); a2 += bf2f(v[2]); a3 += bf2f(v[3]);
          a4 += bf2f(v[4]); a5 += bf2f(v[5]); a6 += bf2f(v[6]); a7 += bf2f(v[7]);
        }
        bf16x8 mv;
        mv[0] = f2bf(a0 * 0.1f); mv[1] = f2bf(a1 * 0.1f);
        mv[2] = f2bf(a2 * 0.1f); mv[3] = f2bf(a3 * 0.1f);
        mv[4] = f2bf(a4 * 0.1f); mv[5] = f2bf(a5 * 0.1f);
        mv[6] = f2bf(a6 * 0.1f); mv[7] = f2bf(a7 * 0.1f);
        *reinterpret_cast<bf16x8*>(&As[r][c * 8]) = sv;
        *reinterpret_cast<bf16x8*>(&As[r][256 + c * 8]) = mv;
      } else {
        bf16x8 z = {0, 0, 0, 0, 0, 0, 0, 0};
        *reinterpret_cast<bf16x8*>(&As[r][c * 8]) = z;
        *reinterpret_cast<bf16x8*>(&As[r][256 + c * 8]) = z;
      }
    }
  }
  __syncthreads();

  // ---- GEMM phase: 32x256 = 4 waves x (32x64), K=512 ----
  const int wave = tid >> 6, lane = tid & 63;
  const int wn = wave * 64;
  const int lr = lane & 15;           // m (A) / n (B) within 16x16 frag
  const int lkb = (lane >> 4) * 8;    // k base within 32

  f32x4 acc[2][4] = {};

#pragma unroll 2
  for (int k0 = 0; k0 < 512; k0 += 32) {
    bf16x8 a0 = *reinterpret_cast<const bf16x8*>(&As[lr][k0 + lkb]);
    bf16x8 a1 = *reinterpret_cast<const bf16x8*>(&As[16 + lr][k0 + lkb]);
    bf16x8 b0 = *reinterpret_cast<const bf16x8*>(Wb + (size_t)(wn + 0 + lr) * 512 + k0 + lkb);
    bf16x8 b1 = *reinterpret_cast<const bf16x8*>(Wb + (size_t)(wn + 16 + lr) * 512 + k0 + lkb);
    bf16x8 b2 = *reinterpret_cast<const bf16x8*>(Wb + (size_t)(wn + 32 + lr) * 512 + k0 + lkb);
    bf16x8 b3 = *reinterpret_cast<const bf16x8*>(Wb + (size_t)(wn + 48 + lr) * 512 + k0 + lkb);

    acc[0][0] = __builtin_amdgcn_mfma_f32_16x16x32_bf16(a0, b0, acc[0][0], 0, 0, 0);
    acc[1][0] = __builtin_amdgcn_mfma_f32_16x16x32_bf16(a1, b0, acc[1][0], 0, 0, 0);
    acc[0][1] = __builtin_amdgcn_mfma_f32_16x16x32_bf16(a0, b1, acc[0][1], 0, 0, 0);
    acc[1][1] = __builtin_amdgcn_mfma_f32_16x16x32_bf16(a1, b1, acc[1][1], 0, 0, 0);
    acc[0][2] = __builtin_amdgcn_mfma_f32_16x16x32_bf16(a0, b2, acc[0][2], 0, 0, 0);
    acc[1][2] = __builtin_amdgcn_mfma_f32_16x16x32_bf16(a1, b2, acc[1][2], 0, 0, 0);
    acc[0][3] = __builtin_amdgcn_mfma_f32_16x16x32_bf16(a0, b3, acc[0][3], 0, 0, 0);
    acc[1][3] = __builtin_amdgcn_mfma_f32_16x16x32_bf16(a1, b3, acc[1][3], 0, 0, 0);
  }

  // ---- epilogue: relu + store ----
#pragma unroll
  for (int mi = 0; mi < 2; ++mi)
#pragma unroll
    for (int ni = 0; ni < 4; ++ni)
#pragma unroll
      for (int r = 0; r < 4; ++r) {
        const int gm = m0 + mi * 16 + (lane >> 4) * 4 + r;
        const int gn = wn + ni * 16 + lr;
        float v = acc[mi][ni][r];
        v = v > 0.f ? v : 0.f;
        if (gm < Nvalid) {
          if (OUT_BF16)
            reinterpret_cast<short*>(out)[(size_t)gm * 256 + gn] = f2bf(v);
          else
            reinterpret_cast<float*>(out)[(size_t)gm * 256 + gn] = v;
        }
      }
}

extern "C" void kernel_launch(void* const* d_in, const int* in_sizes, int n_in,
                              void* d_out, int out_size, void* d_ws, size_t ws_size,
                              hipStream_t stream) {
  const float* raw = (const float*)d_in[0];
  const float* W1 = (const float*)d_in[1];
  const float* W2 = (const float*)d_in[2];
  const int* nodes1 = (const int*)d_in[3];
  const int* neigh1 = (const int*)d_in[4];
  const int* self2 = (const int*)d_in[5];
  const int* neigh2 = (const int*)d_in[6];
  float* out = (float*)d_out;

  const int N_RAW = 200000, N1 = 100000, N2 = 20000;

  short* rawb = (short*)d_ws;                         // 200000*256 bf16 = 102.4 MB
  short* h1 = rawb + (size_t)N_RAW * 256;             // 100000*256 bf16 = 51.2 MB
  short* W1b = h1 + (size_t)N1 * 256;                 // 131072 bf16
  short* W2b = W1b + 131072;                          // 131072 bf16

  convert_w<<<512, 256, 0, stream>>>(W1, W1b, 131072);
  convert_w<<<512, 256, 0, stream>>>(W2, W2b, 131072);
  convert_raw<<<(N_RAW * 256 / 8) / 256, 256, 0, stream>>>(raw, rawb);

  sage_fused<true><<<N1 / 32, 256, 0, stream>>>(rawb, nodes1, neigh1, W1b, h1, N1);
  sage_fused<false><<<N2 / 32, 256, 0, stream>>>(h1, self2, neigh2, W2b, out, N2);
}

// Round 3
// 225.974 us; speedup vs baseline: 1.3271x; 1.0816x over previous
//
#include <hip/hip_runtime.h>
#include <hip/hip_bf16.h>

// GraphSAGE 2-layer, fused: per-block {gather+mean -> LDS} then {MFMA GEMM}.
// N_RAW=200000, N1=100000, N2=20000, K=10, D=256, OUT=256.
// 100000/32=3125, 20000/32=625 -> exact 32-row tiles, no bounds checks needed.

typedef __attribute__((ext_vector_type(8))) short bf16x8;
typedef __attribute__((ext_vector_type(4))) float f32x4;

static __device__ __forceinline__ short f2bf(float f) {
  __hip_bfloat16 h = __float2bfloat16(f);
  return *reinterpret_cast<short*>(&h);
}
static __device__ __forceinline__ float bf2f(short s) {
  union { unsigned u; float f; } x;
  x.u = ((unsigned)(unsigned short)s) << 16;
  return x.f;
}

// ---------------- one-shot f32 -> bf16: raw (25000 blocks) + W1 (64) + W2 (64) ----------------
__global__ __launch_bounds__(256) void convert_all(
    const float* __restrict__ raw, const float* __restrict__ W1,
    const float* __restrict__ W2, short* __restrict__ rawb,
    short* __restrict__ W1b, short* __restrict__ W2b) {
  const int b = blockIdx.x;
  const float* src;
  short* dst;
  size_t base;
  if (b < 25000) { src = raw; dst = rawb; base = (size_t)b * 2048; }
  else if (b < 25064) { src = W1; dst = W1b; base = (size_t)(b - 25000) * 2048; }
  else { src = W2; dst = W2b; base = (size_t)(b - 25064) * 2048; }
  const size_t i = base + (size_t)threadIdx.x * 8;
  const float4* s4 = reinterpret_cast<const float4*>(src + i);
  float4 u = s4[0], v = s4[1];
  bf16x8 o;
  o[0] = f2bf(u.x); o[1] = f2bf(u.y); o[2] = f2bf(u.z); o[3] = f2bf(u.w);
  o[4] = f2bf(v.x); o[5] = f2bf(v.y); o[6] = f2bf(v.z); o[7] = f2bf(v.w);
  *reinterpret_cast<bf16x8*>(dst + i) = o;
}

// ---------------- fused layer: gather+mean -> LDS -> relu(comb @ W^T) ----------------
// Block: 32 rows x 256 cols, 256 threads (4 waves, each wave 32 rows x 64 cols).
// A in LDS (padded rows). B-frags streamed from global W (256 KB, L2-resident),
// software-pipelined one k-step ahead.
template <bool OUT_BF16>
__global__ __launch_bounds__(256, 4) void sage_fused(
    const short* __restrict__ E,        // [Ne][256] bf16 embeddings
    const int* __restrict__ self_idx,   // [Nv]
    const int* __restrict__ neigh,      // [Nv][10]
    const short* __restrict__ Wb,       // [256][512] bf16
    void* __restrict__ out) {           // [Nv][256] (bf16 or f32)
  __shared__ short As[32][520];

  const int tid = threadIdx.x;
  const int m0 = blockIdx.x * 32;

  // ---- gather + mean phase: all 11 row-loads in flight, then reduce ----
  {
    const int c = tid & 31;    // 16-B chunk (8 bf16) within 256-col row
    const int rs = tid >> 5;   // row slot 0..7 -> rows rs*4 .. rs*4+3
#pragma unroll
    for (int rr = 0; rr < 4; ++rr) {
      const int r = rs * 4 + rr;
      const int gr = m0 + r;
      const int si = self_idx[gr];
      int nb[10];
#pragma unroll
      for (int k = 0; k < 10; ++k) nb[k] = neigh[gr * 10 + k];
      bf16x8 sv = *reinterpret_cast<const bf16x8*>(E + (size_t)si * 256 + c * 8);
      bf16x8 v[10];
#pragma unroll
      for (int k = 0; k < 10; ++k)
        v[k] = *reinterpret_cast<const bf16x8*>(E + (size_t)nb[k] * 256 + c * 8);
      bf16x8 mv;
#pragma unroll
      for (int j = 0; j < 8; ++j) {
        float sA = bf2f(v[0][j]) + bf2f(v[2][j]) + bf2f(v[4][j]) + bf2f(v[6][j]) + bf2f(v[8][j]);
        float sB = bf2f(v[1][j]) + bf2f(v[3][j]) + bf2f(v[5][j]) + bf2f(v[7][j]) + bf2f(v[9][j]);
        mv[j] = f2bf((sA + sB) * 0.1f);
      }
      *reinterpret_cast<bf16x8*>(&As[r][c * 8]) = sv;
      *reinterpret_cast<bf16x8*>(&As[r][256 + c * 8]) = mv;
    }
  }
  __syncthreads();

  // ---- GEMM phase: 32x256 = 4 waves x (32x64), K=512, 1-step pipelined ----
  const int wave = tid >> 6, lane = tid & 63;
  const int wn = wave * 64;
  const int lr = lane & 15;           // m (A) / n (B) within 16x16 frag
  const int lkb = (lane >> 4) * 8;    // k base within 32
  const short* Bp = Wb + (size_t)(wn + lr) * 512 + lkb;  // + ni*8192 + k0

  f32x4 acc[2][4] = {};

  bf16x8 a0 = *reinterpret_cast<const bf16x8*>(&As[lr][lkb]);
  bf16x8 a1 = *reinterpret_cast<const bf16x8*>(&As[16 + lr][lkb]);
  bf16x8 b0 = *reinterpret_cast<const bf16x8*>(Bp + 0 * 8192);
  bf16x8 b1 = *reinterpret_cast<const bf16x8*>(Bp + 1 * 8192);
  bf16x8 b2 = *reinterpret_cast<const bf16x8*>(Bp + 2 * 8192);
  bf16x8 b3 = *reinterpret_cast<const bf16x8*>(Bp + 3 * 8192);

#pragma unroll
  for (int ks = 0; ks < 16; ++ks) {
    bf16x8 na0, na1, nb0, nb1, nb2, nb3;
    if (ks < 15) {
      const int k0 = (ks + 1) * 32;
      na0 = *reinterpret_cast<const bf16x8*>(&As[lr][k0 + lkb]);
      na1 = *reinterpret_cast<const bf16x8*>(&As[16 + lr][k0 + lkb]);
      nb0 = *reinterpret_cast<const bf16x8*>(Bp + k0 + 0 * 8192);
      nb1 = *reinterpret_cast<const bf16x8*>(Bp + k0 + 1 * 8192);
      nb2 = *reinterpret_cast<const bf16x8*>(Bp + k0 + 2 * 8192);
      nb3 = *reinterpret_cast<const bf16x8*>(Bp + k0 + 3 * 8192);
    }
    __builtin_amdgcn_s_setprio(1);
    acc[0][0] = __builtin_amdgcn_mfma_f32_16x16x32_bf16(a0, b0, acc[0][0], 0, 0, 0);
    acc[1][0] = __builtin_amdgcn_mfma_f32_16x16x32_bf16(a1, b0, acc[1][0], 0, 0, 0);
    acc[0][1] = __builtin_amdgcn_mfma_f32_16x16x32_bf16(a0, b1, acc[0][1], 0, 0, 0);
    acc[1][1] = __builtin_amdgcn_mfma_f32_16x16x32_bf16(a1, b1, acc[1][1], 0, 0, 0);
    acc[0][2] = __builtin_amdgcn_mfma_f32_16x16x32_bf16(a0, b2, acc[0][2], 0, 0, 0);
    acc[1][2] = __builtin_amdgcn_mfma_f32_16x16x32_bf16(a1, b2, acc[1][2], 0, 0, 0);
    acc[0][3] = __builtin_amdgcn_mfma_f32_16x16x32_bf16(a0, b3, acc[0][3], 0, 0, 0);
    acc[1][3] = __builtin_amdgcn_mfma_f32_16x16x32_bf16(a1, b3, acc[1][3], 0, 0, 0);
    __builtin_amdgcn_s_setprio(0);
    a0 = na0; a1 = na1; b0 = nb0; b1 = nb1; b2 = nb2; b3 = nb3;
  }

  // ---- epilogue: relu + store ----
#pragma unroll
  for (int mi = 0; mi < 2; ++mi)
#pragma unroll
    for (int ni = 0; ni < 4; ++ni)
#pragma unroll
      for (int r = 0; r < 4; ++r) {
        const int gm = m0 + mi * 16 + (lane >> 4) * 4 + r;
        const int gn = wn + ni * 16 + lr;
        float v = acc[mi][ni][r];
        v = v > 0.f ? v : 0.f;
        if (OUT_BF16)
          reinterpret_cast<short*>(out)[(size_t)gm * 256 + gn] = f2bf(v);
        else
          reinterpret_cast<float*>(out)[(size_t)gm * 256 + gn] = v;
      }
}

extern "C" void kernel_launch(void* const* d_in, const int* in_sizes, int n_in,
                              void* d_out, int out_size, void* d_ws, size_t ws_size,
                              hipStream_t stream) {
  const float* raw = (const float*)d_in[0];
  const float* W1 = (const float*)d_in[1];
  const float* W2 = (const float*)d_in[2];
  const int* nodes1 = (const int*)d_in[3];
  const int* neigh1 = (const int*)d_in[4];
  const int* self2 = (const int*)d_in[5];
  const int* neigh2 = (const int*)d_in[6];
  float* out = (float*)d_out;

  const int N_RAW = 200000, N1 = 100000, N2 = 20000;

  short* rawb = (short*)d_ws;                         // 200000*256 bf16 = 102.4 MB
  short* h1 = rawb + (size_t)N_RAW * 256;             // 100000*256 bf16 = 51.2 MB
  short* W1b = h1 + (size_t)N1 * 256;                 // 131072 bf16
  short* W2b = W1b + 131072;                          // 131072 bf16

  convert_all<<<25128, 256, 0, stream>>>(raw, W1, W2, rawb, W1b, W2b);
  sage_fused<true><<<N1 / 32, 256, 0, stream>>>(rawb, nodes1, neigh1, W1b, h1);
  sage_fused<false><<<N2 / 32, 256, 0, stream>>>(h1, self2, neigh2, W2b, out);
}